// Round 7
// baseline (195.808 us; speedup 1.0000x reference)
//
#include <hip/hip_runtime.h>

// B=2, S=2048, D=1024, H=16, hd=64, SCALE=32.
// softmax over batch axis (B=2) == pointwise sigmoid((s0-s1)/32); no k-normalization.
// Sigmoid scale log2(e)/32 is folded into Q at the QKV-GEMM epilogue.
// NOTE: p1 must be computed as 1-p0 (NOT p0*e): e=exp2(dS) overflows to inf -> 0*inf=NaN.
// LDS: unpadded 64-f16 rows + XOR chunk swizzle (chunk ^= row&7) -> conflict-free b128.

typedef _Float16 f16;
typedef __attribute__((ext_vector_type(8))) _Float16 f16x8;
typedef __attribute__((ext_vector_type(4))) _Float16 f16x4;
typedef __attribute__((ext_vector_type(4))) float f32x4;

#define MFMA16(a,b,c) __builtin_amdgcn_mfma_f32_16x16x32_f16(a,b,c,0,0,0)
#define GLD16(gp, lp) __builtin_amdgcn_global_load_lds(                         \
    (const __attribute__((address_space(1))) void*)(gp),                        \
    (__attribute__((address_space(3))) void*)(lp), 16, 0, 0)

// ---------------- x: fp32 -> fp16 ----------------
__global__ __launch_bounds__(256) void convert_x(const float* __restrict__ x,
                                                 f16* __restrict__ xh, int n4) {
    int i = blockIdx.x * 256 + threadIdx.x;
    if (i >= n4) return;
    float4 v = ((const float4*)x)[i];
    f16x4 h;
    h[0] = (f16)v.x; h[1] = (f16)v.y; h[2] = (f16)v.z; h[3] = (f16)v.w;
    *(f16x4*)(xh + (long)i * 4) = h;
}

// ---------------- weights: fp32 [1024][1024] -> fp16 transposed ----------------
__global__ __launch_bounds__(256) void transpose_w(const float* __restrict__ w0, const float* __restrict__ w1,
                                                   const float* __restrict__ w2, const float* __restrict__ w3,
                                                   f16* __restrict__ o0, f16* __restrict__ o1,
                                                   f16* __restrict__ o2, f16* __restrict__ o3) {
    const float* w; f16* o;
    switch (blockIdx.z) {
        case 0: w = w0; o = o0; break;
        case 1: w = w1; o = o1; break;
        case 2: w = w2; o = o2; break;
        default: w = w3; o = o3; break;
    }
    __shared__ alignas(16) f16 t[64][72];
    const int tid = threadIdx.x;
    const int d0 = blockIdx.x * 64, j0 = blockIdx.y * 64;
    #pragma unroll
    for (int it = 0; it < 4; ++it) {
        int idx = it * 256 + tid;
        int row = idx >> 4, c4 = idx & 15;
        float4 v = *(const float4*)(w + (long)(d0 + row) * 1024 + j0 + c4 * 4);
        f16x4 h;
        h[0] = (f16)v.x; h[1] = (f16)v.y; h[2] = (f16)v.z; h[3] = (f16)v.w;
        *(f16x4*)&t[row][c4 * 4] = h;
    }
    __syncthreads();
    #pragma unroll
    for (int it = 0; it < 4; ++it) {
        int idx = it * 256 + tid;
        int jr = idx >> 4, d4 = idx & 15;
        f16x4 h;
        #pragma unroll
        for (int m = 0; m < 4; ++m) h[m] = t[d4 * 4 + m][jr];
        *(f16x4*)(o + (long)(j0 + jr) * 1024 + d0 + d4 * 4) = h;
    }
}

// ---------------- fused QKV GEMM: [4096x1024] @ Wt^T, Wt = [wqT;wkT;wvT] [3072][1024] ----------------
// 128x128 tiles, grid(32,24) = 768 blocks = 3/CU. Q/K epilogue staged via LDS -> b128 stores.
__global__ __launch_bounds__(256, 1) void gemm_qkv(const f16* __restrict__ A,
                                                   const f16* __restrict__ Wt,
                                                   f16* __restrict__ Qg,
                                                   f16* __restrict__ Kg,
                                                   f16* __restrict__ Vtg) {
    __shared__ alignas(16) f16 smem[16384];          // As = [0:8192) 128x64, Bs = [8192:) 128x64
    f16* As = smem;
    f16* Bs = smem + 8192;
    const int tid = threadIdx.x;
    const int wave = tid >> 6, lane = tid & 63;
    const int l15 = lane & 15, lq = lane >> 4;
    const int sw = l15 & 7;
    const int m0 = blockIdx.x * 128, n0 = blockIdx.y * 128;
    const int wr = (wave >> 1) * 64, wc = (wave & 1) * 64;
    const int r8 = lane >> 3;
    const int swc8 = ((lane & 7) ^ r8) * 8;

    f32x4 acc[4][4] = {};

    for (int kt = 0; kt < 16; ++kt) {       // K = 1024, BK = 64
        __syncthreads();
        #pragma unroll
        for (int i = 0; i < 4; ++i) {
            GLD16(A  + (long)(m0 + wave * 32 + i * 8 + r8) * 1024 + kt * 64 + swc8, As + (wave * 32 + i * 8) * 64);
            GLD16(Wt + (long)(n0 + wave * 32 + i * 8 + r8) * 1024 + kt * 64 + swc8, Bs + (wave * 32 + i * 8) * 64);
        }
        __syncthreads();
        #pragma unroll
        for (int s2 = 0; s2 < 2; ++s2) {
            const int rc = ((s2 * 4 + lq) ^ sw) << 3;
            f16x8 af[4], bf[4];
            #pragma unroll
            for (int i = 0; i < 4; ++i) af[i] = *(const f16x8*)&As[(wr + i * 16 + l15) * 64 + rc];
            #pragma unroll
            for (int j = 0; j < 4; ++j) bf[j] = *(const f16x8*)&Bs[(wc + j * 16 + l15) * 64 + rc];
            #pragma unroll
            for (int i = 0; i < 4; ++i)
                #pragma unroll
                for (int j = 0; j < 4; ++j)
                    acc[i][j] = MFMA16(af[i], bf[j], acc[i][j]);
        }
    }

    const int sel = n0 >> 10;                       // 0:Q 1:K 2:V (block-uniform)
    const int nb = n0 - (sel << 10);

    if (sel < 2) {
        // LDS-staged coalesced epilogue for Q/K ([b][h][s][64]); Q gets sigmoid scale folded in.
        f16* dst = sel == 0 ? Qg : Kg;
        const float qs = sel == 0 ? 0.045084219f : 1.0f;   // log2(e)/32
        __syncthreads();
        #pragma unroll
        for (int i = 0; i < 4; ++i)
            #pragma unroll
            for (int j = 0; j < 4; ++j) {
                int row0 = wr + i * 16 + lq * 4;
                int colb = wc + j * 16 + l15;
                int chunk = colb >> 3, sub = colb & 7;
                #pragma unroll
                for (int r = 0; r < 4; ++r) {
                    int row = row0 + r;
                    smem[row * 128 + ((chunk ^ (row & 7)) << 3) + sub] = (f16)(acc[i][j][r] * qs);
                }
            }
        __syncthreads();
        #pragma unroll
        for (int e = 0; e < 8; ++e) {
            int id = e * 256 + tid;
            int row = id >> 4, c = id & 15;
            f16x8 v = *(const f16x8*)&smem[row * 128 + ((c ^ (row & 7)) << 3)];
            int gr = m0 + row, b = gr >> 11, s = gr & 2047;
            int gc = nb + c * 8, hh = gc >> 6, hd = gc & 63;
            *(f16x8*)(dst + (long)((b * 16 + hh) * 2048 + s) * 64 + hd) = v;
        }
    } else {
        #pragma unroll
        for (int i = 0; i < 4; ++i)
            #pragma unroll
            for (int j = 0; j < 4; ++j) {
                int gr0 = m0 + wr + i * 16 + lq * 4;
                int gc  = nb + wc + j * 16 + l15;
                int b = gr0 >> 11, s = gr0 & 2047;
                int hh = gc >> 6, hd = gc & 63;
                f16x4 v;
                #pragma unroll
                for (int r = 0; r < 4; ++r) v[r] = (f16)acc[i][j][r];
                *(f16x4*)(Vtg + (long)((b * 16 + hh) * 64 + hd) * 2048 + s) = v;
            }
    }
}

// ---------------- output GEMM: fp32 out = (vals0+vals1) @ woT^T ----------------
// BM=64, BN=128 -> grid(64,8) = 512 blocks = 2/CU.
__global__ __launch_bounds__(256, 1) void gemm_out(const f16* __restrict__ A0,
                                                   const f16* __restrict__ A1,
                                                   const f16* __restrict__ Bt,
                                                   float* __restrict__ outp) {
    __shared__ alignas(16) f16 As[64][72];
    __shared__ alignas(16) f16 Bs[128][64];
    const int tid = threadIdx.x;
    const int wave = tid >> 6, lane = tid & 63;
    const int l15 = lane & 15, lq = lane >> 4;
    const int sw = l15 & 7;
    const int m0 = blockIdx.x * 64, n0 = blockIdx.y * 128;
    const int wr = (wave >> 1) * 32, wc = (wave & 1) * 64;
    const int r8 = lane >> 3;
    const int swc8 = ((lane & 7) ^ r8) * 8;

    f32x4 acc[2][4] = {};

    for (int kt = 0; kt < 16; ++kt) {
        __syncthreads();
        #pragma unroll
        for (int it = 0; it < 2; ++it) {
            int idx = it * 256 + tid;
            int row = idx >> 3, c = idx & 7;
            f16x8 a = *(const f16x8*)(A0 + (long)(m0 + row) * 1024 + kt * 64 + c * 8)
                    + *(const f16x8*)(A1 + (long)(m0 + row) * 1024 + kt * 64 + c * 8);
            *(f16x8*)&As[row][c * 8] = a;
        }
        #pragma unroll
        for (int i = 0; i < 4; ++i)
            GLD16(Bt + (long)(n0 + wave * 32 + i * 8 + r8) * 1024 + kt * 64 + swc8, &Bs[wave * 32 + i * 8][0]);
        __syncthreads();
        #pragma unroll
        for (int s2 = 0; s2 < 2; ++s2) {
            const int rc = ((s2 * 4 + lq) ^ sw) << 3;
            f16x8 af[2], bf[4];
            #pragma unroll
            for (int i = 0; i < 2; ++i) af[i] = *(const f16x8*)&As[wr + i * 16 + l15][s2 * 32 + lq * 8];
            #pragma unroll
            for (int j = 0; j < 4; ++j) bf[j] = *(const f16x8*)&Bs[wc + j * 16 + l15][rc];
            #pragma unroll
            for (int i = 0; i < 2; ++i)
                #pragma unroll
                for (int j = 0; j < 4; ++j)
                    acc[i][j] = MFMA16(af[i], bf[j], acc[i][j]);
        }
    }

    #pragma unroll
    for (int i = 0; i < 2; ++i)
        #pragma unroll
        for (int j = 0; j < 4; ++j) {
            int gr0 = m0 + wr + i * 16 + lq * 4;
            int gc  = n0 + wc + j * 16 + l15;
            #pragma unroll
            for (int r = 0; r < 4; ++r)
                outp[(long)(gr0 + r) * 1024 + gc] = acc[i][j][r];
        }
}

// ---------------- fused batch-coupled attention ----------------
// 2-wave blocks: grid = 16h x 32qt(64 rows) x 2ks = 1024 blocks, 40KB LDS -> 4 blocks/CU.
// wave0 stages K (both batches), wave1 stages Vt. Q pre-scaled by log2(e)/32.
__global__ __launch_bounds__(128, 2) void attention_kernel(const f16* __restrict__ Qg,
                                                           const f16* __restrict__ Kg,
                                                           const f16* __restrict__ Vtg,
                                                           f16* __restrict__ vals0,
                                                           f16* __restrict__ vals1) {
    __shared__ alignas(16) f16 Ks [2][64][64];
    __shared__ alignas(16) f16 Vts[2][64][64];
    __shared__ alignas(16) f16 Ps [2][32][64];
    const int tid = threadIdx.x;
    const int wave = tid >> 6, lane = tid & 63;
    const int l15 = lane & 15, lq = lane >> 4;
    const int sw = l15 & 7;

    const int bid = blockIdx.x;
    const int xcd = bid & 7, sl = bid >> 3;          // sl 0..127
    const int h  = xcd * 2 + (sl & 1);               // head pinned to XCD
    const int qt = (sl >> 1) & 31, ks = sl >> 6;
    const int q0 = qt * 64, kt0 = ks * 16;
    f16* vals = ks ? vals1 : vals0;
    const int qr = q0 + wave * 32;

    f16x8 qfr[2][2][2];
    #pragma unroll
    for (int b2 = 0; b2 < 2; ++b2)
        #pragma unroll
        for (int qq = 0; qq < 2; ++qq)
            #pragma unroll
            for (int s2 = 0; s2 < 2; ++s2)
                qfr[b2][qq][s2] = *(const f16x8*)(Qg + (long)((b2 * 16 + h) * 2048 + qr + qq * 16 + l15) * 64
                                                  + s2 * 32 + lq * 8);

    f32x4 acc[2][2][4] = {};

    const int r8 = lane >> 3;
    const int swc8 = ((lane & 7) ^ r8) * 8;
    const f16* kb0 = Kg  + (long)(h * 2048 + kt0 * 64) * 64 + r8 * 64 + swc8;
    const f16* kb1 = kb0 + (long)16 * 2048 * 64;
    const f16* vb0 = Vtg + (long)(h * 64 + r8) * 2048 + kt0 * 64 + swc8;
    const f16* vb1 = vb0 + (long)16 * 64 * 2048;

    for (int kt = 0; kt < 16; ++kt) {
        __syncthreads();
        if (wave == 0) {
            const f16* g0 = kb0 + kt * 4096;
            const f16* g1 = kb1 + kt * 4096;
            #pragma unroll
            for (int i = 0; i < 8; ++i) GLD16(g0 + i * 512, &Ks[0][0][0] + i * 512);
            #pragma unroll
            for (int i = 0; i < 8; ++i) GLD16(g1 + i * 512, &Ks[1][0][0] + i * 512);
        } else {
            const f16* g0 = vb0 + kt * 64;
            const f16* g1 = vb1 + kt * 64;
            #pragma unroll
            for (int i = 0; i < 8; ++i) GLD16(g0 + (long)i * 8 * 2048, &Vts[0][0][0] + i * 512);
            #pragma unroll
            for (int i = 0; i < 8; ++i) GLD16(g1 + (long)i * 8 * 2048, &Vts[1][0][0] + i * 512);
        }
        __syncthreads();

        f16x4 pp0[2][4], pp1[2][4];
        #pragma unroll
        for (int kf = 0; kf < 4; ++kf) {
            f32x4 S0[2] = {}, S1[2] = {};
            #pragma unroll
            for (int s2 = 0; s2 < 2; ++s2) {
                const int rc = ((s2 * 4 + lq) ^ sw) << 3;
                f16x8 a0 = *(const f16x8*)&Ks[0][kf * 16 + l15][rc];
                f16x8 a1 = *(const f16x8*)&Ks[1][kf * 16 + l15][rc];
                #pragma unroll
                for (int qq = 0; qq < 2; ++qq) {
                    S0[qq] = MFMA16(a0, qfr[0][qq][s2], S0[qq]);
                    S1[qq] = MFMA16(a1, qfr[1][qq][s2], S1[qq]);
                }
            }
            #pragma unroll
            for (int qq = 0; qq < 2; ++qq)
                #pragma unroll
                for (int r = 0; r < 4; ++r) {
                    float e = __builtin_amdgcn_exp2f(S1[qq][r] - S0[qq][r]);   // scale pre-folded into Q
                    float p = __builtin_amdgcn_rcpf(1.0f + e);                 // e=inf -> p=0 (safe)
                    pp0[qq][kf][r] = (f16)p;
                    pp1[qq][kf][r] = (f16)(1.0f - p);                          // NOT p*e: 0*inf=NaN
                }
        }

        const int pwsub = (lq & 1) << 2;
        #pragma unroll
        for (int pb = 0; pb < 2; ++pb) {
            #pragma unroll
            for (int qq = 0; qq < 2; ++qq)
                #pragma unroll
                for (int kf = 0; kf < 4; ++kf)
                    *(f16x4*)&Ps[wave][qq * 16 + l15][(((2 * kf + (lq >> 1)) ^ sw) << 3) + pwsub]
                        = pb ? pp1[qq][kf] : pp0[qq][kf];
            #pragma unroll
            for (int s2 = 0; s2 < 2; ++s2) {
                const int rc = ((s2 * 4 + lq) ^ sw) << 3;
                f16x8 pf[2], vf[4];
                #pragma unroll
                for (int qq = 0; qq < 2; ++qq)
                    pf[qq] = *(const f16x8*)&Ps[wave][qq * 16 + l15][rc];
                #pragma unroll
                for (int hf = 0; hf < 4; ++hf)
                    vf[hf] = *(const f16x8*)&Vts[pb][hf * 16 + l15][rc];
                #pragma unroll
                for (int qq = 0; qq < 2; ++qq)
                    #pragma unroll
                    for (int hf = 0; hf < 4; ++hf)
                        acc[pb][qq][hf] = MFMA16(pf[qq], vf[hf], acc[pb][qq][hf]);
            }
        }
    }

    #pragma unroll
    for (int b2 = 0; b2 < 2; ++b2)
        #pragma unroll
        for (int qq = 0; qq < 2; ++qq)
            #pragma unroll
            for (int hf = 0; hf < 4; ++hf)
                #pragma unroll
                for (int r = 0; r < 4; ++r)
                    vals[(long)(b2 * 2048 + qr + qq * 16 + lq * 4 + r) * 1024 + h * 64 + hf * 16 + l15]
                        = (f16)acc[b2][qq][hf][r];
}

extern "C" void kernel_launch(void* const* d_in, const int* in_sizes, int n_in,
                              void* d_out, int out_size, void* d_ws, size_t ws_size,
                              hipStream_t stream) {
    const float* x  = (const float*)d_in[0];
    const float* wq = (const float*)d_in[1];
    const float* wk = (const float*)d_in[2];
    const float* wv = (const float*)d_in[3];
    const float* wo = (const float*)d_in[4];

    char* ws = (char*)d_ws;
    f16* xh    = (f16*)(ws);                   // 8 MiB; dead after QKV gemm -> reused as vals0
    f16* wqT   = (f16*)(ws + 8388608);         // wqT,wkT,wvT contiguous = fused [3072][1024]
    f16* wkT   = (f16*)(ws + 10485760);
    f16* wvT   = (f16*)(ws + 12582912);
    f16* woT   = (f16*)(ws + 14680064);
    f16* Qg    = (f16*)(ws + 16777216);        // [2][16][2048][64] (pre-scaled by log2e/32)
    f16* Kg    = (f16*)(ws + 25165824);
    f16* Vtg   = (f16*)(ws + 33554432);        // [2][16][64][2048]
    f16* vals1 = (f16*)(ws + 41943040);
    f16* vals0 = xh;
    (void)ws_size; (void)in_sizes; (void)n_in; (void)out_size;

    convert_x<<<4096, 256, 0, stream>>>(x, xh, (2 * 2048 * 1024) / 4);
    transpose_w<<<dim3(16, 16, 4), 256, 0, stream>>>(wq, wk, wv, wo, wqT, wkT, wvT, woT);

    gemm_qkv<<<dim3(32, 24), 256, 0, stream>>>(xh, wqT, Qg, Kg, Vtg);

    attention_kernel<<<1024, 128, 0, stream>>>(Qg, Kg, Vtg, vals0, vals1);

    gemm_out<<<dim3(64, 8), 256, 0, stream>>>(vals0, vals1, woT, (float*)d_out);
}

// Round 8
// 187.409 us; speedup vs baseline: 1.0448x; 1.0448x over previous
//
#include <hip/hip_runtime.h>

// B=2, S=2048, D=1024, H=16, hd=64, SCALE=32.
// softmax over batch axis (B=2) == pointwise sigmoid((s0-s1)/32); no k-normalization.
// Sigmoid scale log2(e)/32 is folded into Q at the QKV-GEMM epilogue.
// NOTE: p1 must be 1-p0 (NOT p0*e): e=exp2(dS) overflows to inf -> 0*inf=NaN.
// LDS: unpadded 64-f16 rows + XOR chunk swizzle (chunk ^= row&7) -> conflict-free b128.

typedef _Float16 f16;
typedef __attribute__((ext_vector_type(8))) _Float16 f16x8;
typedef __attribute__((ext_vector_type(4))) _Float16 f16x4;
typedef __attribute__((ext_vector_type(4))) float f32x4;

#define MFMA16(a,b,c) __builtin_amdgcn_mfma_f32_16x16x32_f16(a,b,c,0,0,0)
#define GLD16(gp, lp) __builtin_amdgcn_global_load_lds(                         \
    (const __attribute__((address_space(1))) void*)(gp),                        \
    (__attribute__((address_space(3))) void*)(lp), 16, 0, 0)

// ---------------- fused prep: w transposes (blocks 0..1023) + x convert (1024..5119) ----------------
__global__ __launch_bounds__(256) void prep(const float* __restrict__ x,
                                            const float* __restrict__ w0, const float* __restrict__ w1,
                                            const float* __restrict__ w2, const float* __restrict__ w3,
                                            f16* __restrict__ xh,
                                            f16* __restrict__ o0, f16* __restrict__ o1,
                                            f16* __restrict__ o2, f16* __restrict__ o3) {
    const int bb = blockIdx.x;
    const int tid = threadIdx.x;
    if (bb >= 1024) {
        int i = (bb - 1024) * 256 + tid;
        float4 v = ((const float4*)x)[i];
        f16x4 h;
        h[0] = (f16)v.x; h[1] = (f16)v.y; h[2] = (f16)v.z; h[3] = (f16)v.w;
        *(f16x4*)(xh + (long)i * 4) = h;
        return;
    }
    const float* w; f16* o;
    switch (bb & 3) {
        case 0: w = w0; o = o0; break;
        case 1: w = w1; o = o1; break;
        case 2: w = w2; o = o2; break;
        default: w = w3; o = o3; break;
    }
    __shared__ alignas(16) f16 t[64][72];
    const int d0 = ((bb >> 2) & 15) * 64, j0 = (bb >> 6) * 64;
    #pragma unroll
    for (int it = 0; it < 4; ++it) {
        int idx = it * 256 + tid;
        int row = idx >> 4, c4 = idx & 15;
        float4 v = *(const float4*)(w + (long)(d0 + row) * 1024 + j0 + c4 * 4);
        f16x4 h;
        h[0] = (f16)v.x; h[1] = (f16)v.y; h[2] = (f16)v.z; h[3] = (f16)v.w;
        *(f16x4*)&t[row][c4 * 4] = h;
    }
    __syncthreads();
    #pragma unroll
    for (int it = 0; it < 4; ++it) {
        int idx = it * 256 + tid;
        int jr = idx >> 4, d4 = idx & 15;
        f16x4 h;
        #pragma unroll
        for (int m = 0; m < 4; ++m) h[m] = t[d4 * 4 + m][jr];
        *(f16x4*)(o + (long)(j0 + jr) * 1024 + d0 + d4 * 4) = h;
    }
}

// ---------------- fused QKV GEMM: [4096x1024] @ Wt^T, Wt = [wqT;wkT;wvT] [3072][1024] ----------------
// 128x128 tiles, grid(32,24) = 768 blocks = 3/CU. Q/K epilogue staged via LDS -> b128 stores.
__global__ __launch_bounds__(256, 1) void gemm_qkv(const f16* __restrict__ A,
                                                   const f16* __restrict__ Wt,
                                                   f16* __restrict__ Qg,
                                                   f16* __restrict__ Kg,
                                                   f16* __restrict__ Vtg) {
    __shared__ alignas(16) f16 smem[16384];          // As = [0:8192) 128x64, Bs = [8192:) 128x64
    f16* As = smem;
    f16* Bs = smem + 8192;
    const int tid = threadIdx.x;
    const int wave = tid >> 6, lane = tid & 63;
    const int l15 = lane & 15, lq = lane >> 4;
    const int sw = l15 & 7;
    const int m0 = blockIdx.x * 128, n0 = blockIdx.y * 128;
    const int wr = (wave >> 1) * 64, wc = (wave & 1) * 64;
    const int r8 = lane >> 3;
    const int swc8 = ((lane & 7) ^ r8) * 8;

    f32x4 acc[4][4] = {};

    for (int kt = 0; kt < 16; ++kt) {       // K = 1024, BK = 64
        __syncthreads();
        #pragma unroll
        for (int i = 0; i < 4; ++i) {
            GLD16(A  + (long)(m0 + wave * 32 + i * 8 + r8) * 1024 + kt * 64 + swc8, As + (wave * 32 + i * 8) * 64);
            GLD16(Wt + (long)(n0 + wave * 32 + i * 8 + r8) * 1024 + kt * 64 + swc8, Bs + (wave * 32 + i * 8) * 64);
        }
        __syncthreads();
        #pragma unroll
        for (int s2 = 0; s2 < 2; ++s2) {
            const int rc = ((s2 * 4 + lq) ^ sw) << 3;
            f16x8 af[4], bf[4];
            #pragma unroll
            for (int i = 0; i < 4; ++i) af[i] = *(const f16x8*)&As[(wr + i * 16 + l15) * 64 + rc];
            #pragma unroll
            for (int j = 0; j < 4; ++j) bf[j] = *(const f16x8*)&Bs[(wc + j * 16 + l15) * 64 + rc];
            #pragma unroll
            for (int i = 0; i < 4; ++i)
                #pragma unroll
                for (int j = 0; j < 4; ++j)
                    acc[i][j] = MFMA16(af[i], bf[j], acc[i][j]);
        }
    }

    const int sel = n0 >> 10;                       // 0:Q 1:K 2:V (block-uniform)
    const int nb = n0 - (sel << 10);

    if (sel < 2) {
        f16* dst = sel == 0 ? Qg : Kg;
        const float qs = sel == 0 ? 0.045084219f : 1.0f;   // log2(e)/32
        __syncthreads();
        #pragma unroll
        for (int i = 0; i < 4; ++i)
            #pragma unroll
            for (int j = 0; j < 4; ++j) {
                int row0 = wr + i * 16 + lq * 4;
                int colb = wc + j * 16 + l15;
                int chunk = colb >> 3, sub = colb & 7;
                #pragma unroll
                for (int r = 0; r < 4; ++r) {
                    int row = row0 + r;
                    smem[row * 128 + ((chunk ^ (row & 7)) << 3) + sub] = (f16)(acc[i][j][r] * qs);
                }
            }
        __syncthreads();
        #pragma unroll
        for (int e = 0; e < 8; ++e) {
            int id = e * 256 + tid;
            int row = id >> 4, c = id & 15;
            f16x8 v = *(const f16x8*)&smem[row * 128 + ((c ^ (row & 7)) << 3)];
            int gr = m0 + row, b = gr >> 11, s = gr & 2047;
            int gc = nb + c * 8, hh = gc >> 6, hd = gc & 63;
            *(f16x8*)(dst + (long)((b * 16 + hh) * 2048 + s) * 64 + hd) = v;
        }
    } else {
        #pragma unroll
        for (int i = 0; i < 4; ++i)
            #pragma unroll
            for (int j = 0; j < 4; ++j) {
                int gr0 = m0 + wr + i * 16 + lq * 4;
                int gc  = nb + wc + j * 16 + l15;
                int b = gr0 >> 11, s = gr0 & 2047;
                int hh = gc >> 6, hd = gc & 63;
                f16x4 v;
                #pragma unroll
                for (int r = 0; r < 4; ++r) v[r] = (f16)acc[i][j][r];
                *(f16x4*)(Vtg + (long)((b * 16 + hh) * 64 + hd) * 2048 + s) = v;
            }
    }
}

// ---------------- output GEMM: fp32 out = (vals0+vals1) @ woT^T ----------------
// BM=64, BN=128 -> grid(64,8) = 512 blocks = 2/CU.
__global__ __launch_bounds__(256, 1) void gemm_out(const f16* __restrict__ A0,
                                                   const f16* __restrict__ A1,
                                                   const f16* __restrict__ Bt,
                                                   float* __restrict__ outp) {
    __shared__ alignas(16) f16 As[64][72];
    __shared__ alignas(16) f16 Bs[128][64];
    const int tid = threadIdx.x;
    const int wave = tid >> 6, lane = tid & 63;
    const int l15 = lane & 15, lq = lane >> 4;
    const int sw = l15 & 7;
    const int m0 = blockIdx.x * 64, n0 = blockIdx.y * 128;
    const int wr = (wave >> 1) * 32, wc = (wave & 1) * 64;
    const int r8 = lane >> 3;
    const int swc8 = ((lane & 7) ^ r8) * 8;

    f32x4 acc[2][4] = {};

    for (int kt = 0; kt < 16; ++kt) {
        __syncthreads();
        #pragma unroll
        for (int it = 0; it < 2; ++it) {
            int idx = it * 256 + tid;
            int row = idx >> 3, c = idx & 7;
            f16x8 a = *(const f16x8*)(A0 + (long)(m0 + row) * 1024 + kt * 64 + c * 8)
                    + *(const f16x8*)(A1 + (long)(m0 + row) * 1024 + kt * 64 + c * 8);
            *(f16x8*)&As[row][c * 8] = a;
        }
        #pragma unroll
        for (int i = 0; i < 4; ++i)
            GLD16(Bt + (long)(n0 + wave * 32 + i * 8 + r8) * 1024 + kt * 64 + swc8, &Bs[wave * 32 + i * 8][0]);
        __syncthreads();
        #pragma unroll
        for (int s2 = 0; s2 < 2; ++s2) {
            const int rc = ((s2 * 4 + lq) ^ sw) << 3;
            f16x8 af[2], bf[4];
            #pragma unroll
            for (int i = 0; i < 2; ++i) af[i] = *(const f16x8*)&As[wr + i * 16 + l15][s2 * 32 + lq * 8];
            #pragma unroll
            for (int j = 0; j < 4; ++j) bf[j] = *(const f16x8*)&Bs[wc + j * 16 + l15][rc];
            #pragma unroll
            for (int i = 0; i < 2; ++i)
                #pragma unroll
                for (int j = 0; j < 4; ++j)
                    acc[i][j] = MFMA16(af[i], bf[j], acc[i][j]);
        }
    }

    #pragma unroll
    for (int i = 0; i < 2; ++i)
        #pragma unroll
        for (int j = 0; j < 4; ++j) {
            int gr0 = m0 + wr + i * 16 + lq * 4;
            int gc  = n0 + wc + j * 16 + l15;
            #pragma unroll
            for (int r = 0; r < 4; ++r)
                outp[(long)(gr0 + r) * 1024 + gc] = acc[i][j][r];
        }
}

// ---------------- fused batch-coupled attention, split-k x2, K/V double-buffered ----------------
// R5 geometry: 512 blocks x 256 thr, head XCD-pinned. One barrier per k-tile; loads for
// tile kt+1 issued right after the barrier publishing kt -> vmcnt drain hidden by compute.
__global__ __launch_bounds__(256, 2) void attention_kernel(const f16* __restrict__ Qg,
                                                           const f16* __restrict__ Kg,
                                                           const f16* __restrict__ Vtg,
                                                           f16* __restrict__ vals0,
                                                           f16* __restrict__ vals1) {
    __shared__ alignas(16) f16 Ks [2][2][64][64];    // [buf][batch]
    __shared__ alignas(16) f16 Vts[2][2][64][64];
    __shared__ alignas(16) f16 Ps [4][32][64];       // wave-private
    const int tid = threadIdx.x;
    const int wave = tid >> 6, lane = tid & 63;
    const int l15 = lane & 15, lq = lane >> 4;
    const int sw = l15 & 7;

    const int bid = blockIdx.x;
    const int xcd = bid & 7, sl = bid >> 3;
    const int h  = xcd * 2 + (sl & 1);               // head pinned to XCD
    const int qt = (sl >> 1) & 15, ks = sl >> 5;
    const int q0 = qt * 128, kt0 = ks * 16;
    f16* vals = ks ? vals1 : vals0;
    const int qr = q0 + wave * 32;

    f16x8 qfr[2][2][2];                              // Q pre-scaled by log2(e)/32
    #pragma unroll
    for (int b2 = 0; b2 < 2; ++b2)
        #pragma unroll
        for (int qq = 0; qq < 2; ++qq)
            #pragma unroll
            for (int s2 = 0; s2 < 2; ++s2)
                qfr[b2][qq][s2] = *(const f16x8*)(Qg + (long)((b2 * 16 + h) * 2048 + qr + qq * 16 + l15) * 64
                                                  + s2 * 32 + lq * 8);

    f32x4 acc[2][2][4] = {};

    const int tb = wave & 1;
    const int r8 = lane >> 3;
    const int swc8 = ((lane & 7) ^ r8) * 8;
    const f16* kbase = Kg  + (long)((tb * 16 + h) * 2048 + kt0 * 64) * 64 + r8 * 64 + swc8;
    const f16* vbase = Vtg + (long)((tb * 16 + h) * 64 + r8) * 2048 + kt0 * 64 + swc8;

    auto stage = [&](int kt, int buf) {
        if (wave < 2) {
            const f16* g = kbase + kt * 4096;
            f16* l = &Ks[buf][tb][0][0];
            #pragma unroll
            for (int i = 0; i < 8; ++i) GLD16(g + i * 512, l + i * 512);
        } else {
            const f16* g = vbase + kt * 64;
            f16* l = &Vts[buf][tb][0][0];
            #pragma unroll
            for (int i = 0; i < 8; ++i) GLD16(g + (long)i * 8 * 2048, l + i * 512);
        }
    };

    stage(0, 0);
    for (int kt = 0; kt < 16; ++kt) {
        const int cur = kt & 1;
        __syncthreads();                             // publishes buf cur (loads issued last iter)
        if (kt < 15) stage(kt + 1, cur ^ 1);         // prefetch next tile, drained next barrier

        f16x4 pp0[2][4], pp1[2][4];
        #pragma unroll
        for (int kf = 0; kf < 4; ++kf) {
            f32x4 S0[2] = {}, S1[2] = {};
            #pragma unroll
            for (int s2 = 0; s2 < 2; ++s2) {
                const int rc = ((s2 * 4 + lq) ^ sw) << 3;
                f16x8 a0 = *(const f16x8*)&Ks[cur][0][kf * 16 + l15][rc];
                f16x8 a1 = *(const f16x8*)&Ks[cur][1][kf * 16 + l15][rc];
                #pragma unroll
                for (int qq = 0; qq < 2; ++qq) {
                    S0[qq] = MFMA16(a0, qfr[0][qq][s2], S0[qq]);
                    S1[qq] = MFMA16(a1, qfr[1][qq][s2], S1[qq]);
                }
            }
            #pragma unroll
            for (int qq = 0; qq < 2; ++qq)
                #pragma unroll
                for (int r = 0; r < 4; ++r) {
                    float e = __builtin_amdgcn_exp2f(S1[qq][r] - S0[qq][r]);
                    float p = __builtin_amdgcn_rcpf(1.0f + e);                 // e=inf -> p=0 (safe)
                    pp0[qq][kf][r] = (f16)p;
                    pp1[qq][kf][r] = (f16)(1.0f - p);                          // NOT p*e: 0*inf=NaN
                }
        }

        const int pwsub = (lq & 1) << 2;
        #pragma unroll
        for (int pb = 0; pb < 2; ++pb) {
            #pragma unroll
            for (int qq = 0; qq < 2; ++qq)
                #pragma unroll
                for (int kf = 0; kf < 4; ++kf)
                    *(f16x4*)&Ps[wave][qq * 16 + l15][(((2 * kf + (lq >> 1)) ^ sw) << 3) + pwsub]
                        = pb ? pp1[qq][kf] : pp0[qq][kf];
            #pragma unroll
            for (int s2 = 0; s2 < 2; ++s2) {
                const int rc = ((s2 * 4 + lq) ^ sw) << 3;
                f16x8 pf[2], vf[4];
                #pragma unroll
                for (int qq = 0; qq < 2; ++qq)
                    pf[qq] = *(const f16x8*)&Ps[wave][qq * 16 + l15][rc];
                #pragma unroll
                for (int hf = 0; hf < 4; ++hf)
                    vf[hf] = *(const f16x8*)&Vts[cur][pb][hf * 16 + l15][rc];
                #pragma unroll
                for (int qq = 0; qq < 2; ++qq)
                    #pragma unroll
                    for (int hf = 0; hf < 4; ++hf)
                        acc[pb][qq][hf] = MFMA16(pf[qq], vf[hf], acc[pb][qq][hf]);
            }
        }
    }

    #pragma unroll
    for (int b2 = 0; b2 < 2; ++b2)
        #pragma unroll
        for (int qq = 0; qq < 2; ++qq)
            #pragma unroll
            for (int hf = 0; hf < 4; ++hf)
                #pragma unroll
                for (int r = 0; r < 4; ++r)
                    vals[(long)(b2 * 2048 + qr + qq * 16 + lq * 4 + r) * 1024 + h * 64 + hf * 16 + l15]
                        = (f16)acc[b2][qq][hf][r];
}

extern "C" void kernel_launch(void* const* d_in, const int* in_sizes, int n_in,
                              void* d_out, int out_size, void* d_ws, size_t ws_size,
                              hipStream_t stream) {
    const float* x  = (const float*)d_in[0];
    const float* wq = (const float*)d_in[1];
    const float* wk = (const float*)d_in[2];
    const float* wv = (const float*)d_in[3];
    const float* wo = (const float*)d_in[4];

    char* ws = (char*)d_ws;
    f16* xh    = (f16*)(ws);                   // 8 MiB; dead after QKV gemm -> reused as vals0
    f16* wqT   = (f16*)(ws + 8388608);         // wqT,wkT,wvT contiguous = fused [3072][1024]
    f16* wkT   = (f16*)(ws + 10485760);
    f16* wvT   = (f16*)(ws + 12582912);
    f16* woT   = (f16*)(ws + 14680064);
    f16* Qg    = (f16*)(ws + 16777216);        // [2][16][2048][64] (pre-scaled by log2e/32)
    f16* Kg    = (f16*)(ws + 25165824);
    f16* Vtg   = (f16*)(ws + 33554432);        // [2][16][64][2048]
    f16* vals1 = (f16*)(ws + 41943040);
    f16* vals0 = xh;
    (void)ws_size; (void)in_sizes; (void)n_in; (void)out_size;

    prep<<<5120, 256, 0, stream>>>(x, wq, wk, wv, wo, xh, wqT, wkT, wvT, woT);

    gemm_qkv<<<dim3(32, 24), 256, 0, stream>>>(xh, wqT, Qg, Kg, Vtg);

    attention_kernel<<<512, 256, 0, stream>>>(Qg, Kg, Vtg, vals0, vals1);

    gemm_out<<<dim3(64, 8), 256, 0, stream>>>(vals0, vals1, woT, (float*)d_out);
}